// Round 2
// baseline (293.392 us; speedup 1.0000x reference)
//
#include <hip/hip_runtime.h>
#include <hip/hip_bf16.h>

typedef __attribute__((ext_vector_type(8))) short bf16x8;
typedef __attribute__((ext_vector_type(8))) short s16x8;
typedef __attribute__((ext_vector_type(4))) float f32x4;
typedef unsigned short u16;

__device__ __forceinline__ u16 f2bf(float f){
  __hip_bfloat16 h = __float2bfloat16(f);
  return *reinterpret_cast<u16*>(&h);
}
__device__ __forceinline__ float bf2f(u16 u){
  __hip_bfloat16 h;
  *reinterpret_cast<u16*>(&h) = u;
  return __bfloat162float(h);
}

// Merged f32->bf16 convert for x / w_qkv / w_proj.
// w_qkv rows 0..767 (the q-projection rows) are pre-scaled by ATT_SCALE=0.125
// so the scores GEMM directly produces scaled logits (frees mix of all scale muls).
__global__ __launch_bounds__(256) void cvt3_kernel(
    const float* __restrict__ s0, u16* __restrict__ d0, int n0,
    const float* __restrict__ s1, u16* __restrict__ d1, int n1,
    const float* __restrict__ s2, u16* __restrict__ d2, int n2)
{
  int i = blockIdx.x*256 + threadIdx.x;
  const float* s; u16* d; int idx; float sc = 1.f;
  if (i < n0){ s = s0; d = d0; idx = i; }
  else if (i < n0 + n1){
    idx = i - n0; s = s1; d = d1;
    if (idx < 768*192) sc = 0.125f;          // f4-index < 768 rows * 192 f4/row
  } else if (i < n0 + n1 + n2){
    idx = i - n0 - n1; s = s2; d = d2;
  } else return;
  float4 v = reinterpret_cast<const float4*>(s)[idx];
  ushort4 o;
  o.x = f2bf(v.x*sc); o.y = f2bf(v.y*sc); o.z = f2bf(v.z*sc); o.w = f2bf(v.w*sc);
  reinterpret_cast<ushort4*>(d)[idx] = o;
}

// C = A(MxK) * B(NxK)^T, A/B bf16 row-major, batched over blockIdx.z.
// MODE 0: QKV scatter -> Q[B,H,N,D](C0), K[B,H,N,D](C1), Vt[B,H,D,N](C2)
// MODE 1: bf16 store, batch stride sC (scores)
// MODE 2: PV -> tmp[B,N,H,D] bf16 (z = b*12+h)
// MODE 3: fp32 store + bias (projection)
template<int BM, int BN, int MODE>
__global__ __launch_bounds__(256) void gemm_bt(
    const u16* __restrict__ A, const u16* __restrict__ B,
    void* __restrict__ C0, void* __restrict__ C1, void* __restrict__ C2,
    const float* __restrict__ bias,
    int M, int N, int K, int lda, int ldb, long sA, long sB, long sC)
{
  constexpr int BK = 32, LDT = 40;   // +8 pad: 80B row stride, conflict-free-ish, 16B aligned
  __shared__ u16 As[BM*LDT];
  __shared__ u16 Bs[BN*LDT];
  const int z = blockIdx.z;
  const u16* Ab = A + (long)z * sA;
  const u16* Bb = B + (long)z * sB;
  const int bm = blockIdx.x * BM, bn = blockIdx.y * BN;
  const int tid = threadIdx.x, lane = tid & 63, wv = tid >> 6;
  constexpr int WM = BM/2, WN = BN/2, FM = WM/16, FN = WN/16;
  const int wm = (wv >> 1) * WM, wn = (wv & 1) * WN;
  const int quad = lane >> 4, cl = lane & 15;
  f32x4 acc[FM][FN];
  #pragma unroll
  for (int i=0;i<FM;i++)
    #pragma unroll
    for (int j=0;j<FN;j++){ f32x4 zr = {0.f,0.f,0.f,0.f}; acc[i][j] = zr; }
  constexpr int AIT = (BM*BK)/(8*256);
  constexpr int BIT = (BN*BK)/(8*256);

  for (int kb = 0; kb < K; kb += BK){
    __syncthreads();
    #pragma unroll
    for (int sL=0; sL<AIT; sL++){
      int e = tid + sL*256, r = e >> 2, c8 = (e & 3) * 8;
      *reinterpret_cast<float4*>(&As[r*LDT + c8]) =
        *reinterpret_cast<const float4*>(Ab + (long)(bm + r)*lda + kb + c8);
    }
    #pragma unroll
    for (int sL=0; sL<BIT; sL++){
      int e = tid + sL*256, r = e >> 2, c8 = (e & 3) * 8;
      *reinterpret_cast<float4*>(&Bs[r*LDT + c8]) =
        *reinterpret_cast<const float4*>(Bb + (long)(bn + r)*ldb + kb + c8);
    }
    __syncthreads();
    bf16x8 af[FM], bfr[FN];
    #pragma unroll
    for (int i=0;i<FM;i++)
      af[i] = *reinterpret_cast<const bf16x8*>(&As[(wm + i*16 + cl)*LDT + quad*8]);
    #pragma unroll
    for (int j=0;j<FN;j++)
      bfr[j] = *reinterpret_cast<const bf16x8*>(&Bs[(wn + j*16 + cl)*LDT + quad*8]);
    #pragma unroll
    for (int i=0;i<FM;i++)
      #pragma unroll
      for (int j=0;j<FN;j++)
        acc[i][j] = __builtin_amdgcn_mfma_f32_16x16x32_bf16(af[i], bfr[j], acc[i][j], 0, 0, 0);
  }

  #pragma unroll
  for (int i=0;i<FM;i++)
  #pragma unroll
  for (int j=0;j<FN;j++)
  #pragma unroll
  for (int r=0;r<4;r++){
    int gm = bm + wm + i*16 + quad*4 + r;
    int gn = bn + wn + j*16 + cl;
    float v = acc[i][j][r];
    if (MODE == 0){
      int b_ = gm >> 10, n_ = gm & 1023;
      int t3 = (gn >= 1536) ? 2 : ((gn >= 768) ? 1 : 0);
      int rem = gn - t3*768;
      int h = rem >> 6, d = rem & 63;
      u16 hv = f2bf(v);
      if (t3 == 0)      ((u16*)C0)[((long)((b_*12 + h)*1024 + n_))*64 + d] = hv;
      else if (t3 == 1) ((u16*)C1)[((long)((b_*12 + h)*1024 + n_))*64 + d] = hv;
      else              ((u16*)C2)[((long)((b_*12 + h)*64 + d))*1024 + n_] = hv;
    } else if (MODE == 1){
      ((u16*)C0)[(long)z*sC + (long)gm*N + gn] = f2bf(v);
    } else if (MODE == 2){
      int b_ = z / 12, h = z - b_*12;
      ((u16*)C0)[((long)((b_*1024 + gm)*12 + h))*64 + gn] = f2bf(v);
    } else {
      ((float*)C0)[(long)gm*N + gn] = v + bias[gn];
    }
  }
}

// One WAVE per (b,n) row. Each lane owns 16 m-values: m = {l*8..l*8+7} u {512+l*8..+7}.
// Full softmax row in-register: no LDS, no __syncthreads. S logits arrive pre-scaled
// (ATT_SCALE folded into w_qkv q-rows).
__global__ __launch_bounds__(64, 2) void mix_kernel(
    u16* __restrict__ S, const float* __restrict__ mask,
    const float* __restrict__ w_pre, const float* __restrict__ w_post)
{
  const int bid = blockIdx.x;            // 0..4095 = b*1024 + n
  const int b = bid >> 10, n = bid & 1023;
  const int l = threadIdx.x;             // 0..63
  const long base0 = (((long)(b*12))*1024 + n) * 1024;   // h=0 plane, row n
  const int off0 = l*8, off1 = 512 + l*8;

  float smix[12][16];

  // ---- pre-mix: smix[g] = sum_h w_pre[g,h] * S_h  (S already scaled) ----
  #pragma unroll
  for (int h=0; h<12; h++){
    const u16* sr = S + base0 + (long)h*1024*1024;
    bf16x8 v0 = *reinterpret_cast<const bf16x8*>(sr + off0);
    bf16x8 v1 = *reinterpret_cast<const bf16x8*>(sr + off1);
    float sv[16];
    #pragma unroll
    for (int j=0;j<8;j++){ sv[j] = bf2f((u16)v0[j]); sv[8+j] = bf2f((u16)v1[j]); }
    if (h == 0){
      #pragma unroll
      for (int g=0;g<12;g++){
        float w = w_pre[g*12];
        #pragma unroll
        for (int mi=0;mi<16;mi++) smix[g][mi] = w * sv[mi];
      }
    } else {
      #pragma unroll
      for (int g=0;g<12;g++){
        float w = w_pre[g*12 + h];
        #pragma unroll
        for (int mi=0;mi<16;mi++) smix[g][mi] += w * sv[mi];
      }
    }
  }

  // ---- mask term: + (sum_h w_pre[g,h]) * mask[b,n,m] ----
  {
    const float* mr = mask + ((long)(b*1024 + n))*1024;
    float mk[16];
    float4 a0 = *reinterpret_cast<const float4*>(mr + off0);
    float4 a1 = *reinterpret_cast<const float4*>(mr + off0 + 4);
    float4 b0 = *reinterpret_cast<const float4*>(mr + off1);
    float4 b1 = *reinterpret_cast<const float4*>(mr + off1 + 4);
    mk[0]=a0.x; mk[1]=a0.y; mk[2]=a0.z; mk[3]=a0.w;
    mk[4]=a1.x; mk[5]=a1.y; mk[6]=a1.z; mk[7]=a1.w;
    mk[8]=b0.x; mk[9]=b0.y; mk[10]=b0.z; mk[11]=b0.w;
    mk[12]=b1.x; mk[13]=b1.y; mk[14]=b1.z; mk[15]=b1.w;
    #pragma unroll
    for (int g=0;g<12;g++){
      float rs = 0.f;
      #pragma unroll
      for (int h=0;h<12;h++) rs += w_pre[g*12 + h];
      #pragma unroll
      for (int mi=0;mi<16;mi++) smix[g][mi] += rs * mk[mi];
    }
  }

  // ---- softmax over m (16 in-reg + one 64-lane shuffle tree), groups interleaved ----
  float M[12];
  #pragma unroll
  for (int g=0;g<12;g++){
    float a = fmaxf(smix[g][0], smix[g][1]);
    float c = fmaxf(smix[g][2], smix[g][3]);
    float e = fmaxf(smix[g][4], smix[g][5]);
    float f = fmaxf(smix[g][6], smix[g][7]);
    float a2 = fmaxf(smix[g][8], smix[g][9]);
    float c2 = fmaxf(smix[g][10], smix[g][11]);
    float e2 = fmaxf(smix[g][12], smix[g][13]);
    float f2 = fmaxf(smix[g][14], smix[g][15]);
    M[g] = fmaxf(fmaxf(fmaxf(a,c), fmaxf(e,f)), fmaxf(fmaxf(a2,c2), fmaxf(e2,f2)));
  }
  #pragma unroll
  for (int off=32; off>0; off>>=1)
    #pragma unroll
    for (int g=0;g<12;g++) M[g] = fmaxf(M[g], __shfl_xor(M[g], off));

  float L[12];
  #pragma unroll
  for (int g=0;g<12;g++){
    float sum = 0.f;
    #pragma unroll
    for (int mi=0;mi<16;mi++){
      float e = __expf(smix[g][mi] - M[g]);
      smix[g][mi] = e; sum += e;
    }
    L[g] = sum;
  }
  #pragma unroll
  for (int off=32; off>0; off>>=1)
    #pragma unroll
    for (int g=0;g<12;g++) L[g] += __shfl_xor(L[g], off);
  #pragma unroll
  for (int g=0;g<12;g++){
    float inv = 1.0f / L[g];
    #pragma unroll
    for (int mi=0;mi<16;mi++) smix[g][mi] *= inv;
  }

  // ---- post-mix + packed bf16 store, streamed per output head ----
  #pragma unroll
  for (int h=0; h<12; h++){
    float o[16];
    {
      float w = w_post[h*12];
      #pragma unroll
      for (int mi=0;mi<16;mi++) o[mi] = w * smix[0][mi];
    }
    #pragma unroll
    for (int g=1;g<12;g++){
      float w = w_post[h*12 + g];
      #pragma unroll
      for (int mi=0;mi<16;mi++) o[mi] += w * smix[g][mi];
    }
    s16x8 st0, st1;
    #pragma unroll
    for (int j=0;j<8;j++){
      st0[j] = (short)f2bf(o[j]);
      st1[j] = (short)f2bf(o[8+j]);
    }
    u16* orow = S + base0 + (long)h*1024*1024;
    *reinterpret_cast<s16x8*>(orow + off0) = st0;
    *reinterpret_cast<s16x8*>(orow + off1) = st1;
  }
}

extern "C" void kernel_launch(void* const* d_in, const int* in_sizes, int n_in,
                              void* d_out, int out_size, void* d_ws, size_t ws_size,
                              hipStream_t stream)
{
  const float* x      = (const float*)d_in[0];
  const float* mask   = (const float*)d_in[1];
  const float* w_qkv  = (const float*)d_in[2];
  const float* w_proj = (const float*)d_in[3];
  const float* b_proj = (const float*)d_in[4];
  const float* w_pre  = (const float*)d_in[5];
  const float* w_post = (const float*)d_in[6];
  float* out = (float*)d_out;

  u16* xb     = (u16*)d_ws;
  u16* wqkvb  = xb     + 4096l*768;
  u16* wprojb = wqkvb  + 2304l*768;
  u16* Qb     = wprojb + 768l*768;
  u16* Kb     = Qb     + 48l*1024*64;
  u16* Vtb    = Kb     + 48l*1024*64;
  u16* tmpb   = Vtb    + 48l*1024*64;
  u16* Sb     = tmpb   + 4096l*768;
  size_t need = ((size_t)(Sb - xb) + 48ul*1024*1024) * sizeof(u16);
  if (ws_size < need) return;   // insufficient scratch: fail visibly

  const int n0 = 4096*768/4, n1 = 2304*768/4, n2 = 768*768/4;
  cvt3_kernel<<<(n0+n1+n2 + 255)/256, 256, 0, stream>>>(x, xb, n0, w_qkv, wqkvb, n1,
                                                        w_proj, wprojb, n2);

  dim3 gq(4096/128, 2304/128, 1);
  gemm_bt<128,128,0><<<gq, 256, 0, stream>>>(xb, wqkvb, Qb, Kb, Vtb, nullptr,
      4096, 2304, 768, 768, 768, 0, 0, 0);

  dim3 gs(1024/128, 1024/128, 48);
  gemm_bt<128,128,1><<<gs, 256, 0, stream>>>(Qb, Kb, Sb, nullptr, nullptr, nullptr,
      1024, 1024, 64, 64, 64, 1024l*64, 1024l*64, 1024l*1024);

  mix_kernel<<<4096, 64, 0, stream>>>(Sb, mask, w_pre, w_post);

  dim3 gp(1024/128, 1, 48);
  gemm_bt<128,64,2><<<gp, 256, 0, stream>>>(Sb, Vtb, tmpb, nullptr, nullptr, nullptr,
      1024, 64, 1024, 1024, 1024, 1024l*1024, 64l*1024, 0);

  dim3 go(4096/128, 768/128, 1);
  gemm_bt<128,128,3><<<go, 256, 0, stream>>>(tmpb, wprojb, out, nullptr, nullptr, b_proj,
      4096, 768, 768, 768, 768, 0, 0, 0);
}

// Round 3
// 264.732 us; speedup vs baseline: 1.1083x; 1.1083x over previous
//
#include <hip/hip_runtime.h>
#include <hip/hip_bf16.h>

typedef __attribute__((ext_vector_type(8))) short bf16x8;
typedef __attribute__((ext_vector_type(8))) short s16x8;
typedef __attribute__((ext_vector_type(4))) float f32x4;
typedef unsigned short u16;
typedef unsigned int u32;

__device__ __forceinline__ u16 f2bf(float f){
  __hip_bfloat16 h = __float2bfloat16(f);
  return *reinterpret_cast<u16*>(&h);
}
__device__ __forceinline__ float bflo(u32 w){ return __uint_as_float(w << 16); }
__device__ __forceinline__ float bfhi(u32 w){ return __uint_as_float(w & 0xffff0000u); }

// async global->LDS, 16B per lane. LDS dest is wave-uniform base + lane*16 (linear).
__device__ __forceinline__ void gload_lds16(const u16* g, u16* l){
  __builtin_amdgcn_global_load_lds(
      (__attribute__((address_space(1))) u32*)g,
      (__attribute__((address_space(3))) u32*)l, 16, 0, 0);
}

// Merged f32->bf16 convert for x / w_qkv / w_proj.
// w_qkv rows 0..767 (q-projection rows) pre-scaled by ATT_SCALE=0.125 so the
// scores GEMM directly produces scaled logits.
__global__ __launch_bounds__(256) void cvt3_kernel(
    const float* __restrict__ s0, u16* __restrict__ d0, int n0,
    const float* __restrict__ s1, u16* __restrict__ d1, int n1,
    const float* __restrict__ s2, u16* __restrict__ d2, int n2)
{
  int i = blockIdx.x*256 + threadIdx.x;
  const float* s; u16* d; int idx; float sc = 1.f;
  if (i < n0){ s = s0; d = d0; idx = i; }
  else if (i < n0 + n1){
    idx = i - n0; s = s1; d = d1;
    if (idx < 768*192) sc = 0.125f;          // f4-index < 768 rows * 192 f4/row
  } else if (i < n0 + n1 + n2){
    idx = i - n0 - n1; s = s2; d = d2;
  } else return;
  float4 v = reinterpret_cast<const float4*>(s)[idx];
  ushort4 o;
  o.x = f2bf(v.x*sc); o.y = f2bf(v.y*sc); o.z = f2bf(v.z*sc); o.w = f2bf(v.w*sc);
  reinterpret_cast<ushort4*>(d)[idx] = o;
}

// C = A(MxK) * B(NxK)^T, A/B bf16 row-major, batched over blockIdx.z.
// Staging via global_load_lds width=16 into linear [rows][BK] LDS tiles.
// MODE 0: QKV scatter -> Q[B,H,N,D](C0), K[B,H,N,D](C1), Vt[B,H,D,N](C2)
// MODE 1: bf16 store, batch stride sC (scores)
// MODE 2: PV -> tmp[B,N,H,D] bf16 (z = b*12+h)
// MODE 3: fp32 store + bias (projection)
template<int BM, int BN, int MODE>
__global__ __launch_bounds__(256) void gemm_bt(
    const u16* __restrict__ A, const u16* __restrict__ B,
    void* __restrict__ C0, void* __restrict__ C1, void* __restrict__ C2,
    const float* __restrict__ bias,
    int M, int N, int K, int lda, int ldb, long sA, long sB, long sC)
{
  constexpr int BK = 32, LDT = 32;   // linear: required by global_load_lds
  __shared__ __align__(16) u16 As[BM*LDT];
  __shared__ __align__(16) u16 Bs[BN*LDT];
  const int z = blockIdx.z;
  const u16* Ab = A + (long)z * sA;
  const u16* Bb = B + (long)z * sB;
  const int bm = blockIdx.x * BM, bn = blockIdx.y * BN;
  const int tid = threadIdx.x, lane = tid & 63, wv = tid >> 6;
  constexpr int WM = BM/2, WN = BN/2, FM = WM/16, FN = WN/16;
  const int wm = (wv >> 1) * WM, wn = (wv & 1) * WN;
  const int quad = lane >> 4, cl = lane & 15;
  f32x4 acc[FM][FN];
  #pragma unroll
  for (int i=0;i<FM;i++)
    #pragma unroll
    for (int j=0;j<FN;j++){ f32x4 zr = {0.f,0.f,0.f,0.f}; acc[i][j] = zr; }
  constexpr int AIT = (BM*BK)/(8*256);
  constexpr int BIT = (BN*BK)/(8*256);

  for (int kb = 0; kb < K; kb += BK){
    __syncthreads();
    #pragma unroll
    for (int sL=0; sL<AIT; sL++){
      int e = tid + sL*256, r = e >> 2, c8 = (e & 3) * 8;
      gload_lds16(Ab + (long)(bm + r)*lda + kb + c8, &As[e*8]);
    }
    #pragma unroll
    for (int sL=0; sL<BIT; sL++){
      int e = tid + sL*256, r = e >> 2, c8 = (e & 3) * 8;
      gload_lds16(Bb + (long)(bn + r)*ldb + kb + c8, &Bs[e*8]);
    }
    __syncthreads();   // compiler drains vmcnt before barrier
    bf16x8 af[FM], bfr[FN];
    #pragma unroll
    for (int i=0;i<FM;i++)
      af[i] = *reinterpret_cast<const bf16x8*>(&As[(wm + i*16 + cl)*LDT + quad*8]);
    #pragma unroll
    for (int j=0;j<FN;j++)
      bfr[j] = *reinterpret_cast<const bf16x8*>(&Bs[(wn + j*16 + cl)*LDT + quad*8]);
    #pragma unroll
    for (int i=0;i<FM;i++)
      #pragma unroll
      for (int j=0;j<FN;j++)
        acc[i][j] = __builtin_amdgcn_mfma_f32_16x16x32_bf16(af[i], bfr[j], acc[i][j], 0, 0, 0);
  }

  #pragma unroll
  for (int i=0;i<FM;i++)
  #pragma unroll
  for (int j=0;j<FN;j++)
  #pragma unroll
  for (int r=0;r<4;r++){
    int gm = bm + wm + i*16 + quad*4 + r;
    int gn = bn + wn + j*16 + cl;
    float v = acc[i][j][r];
    if (MODE == 0){
      int b_ = gm >> 10, n_ = gm & 1023;
      int t3 = (gn >= 1536) ? 2 : ((gn >= 768) ? 1 : 0);
      int rem = gn - t3*768;
      int h = rem >> 6, d = rem & 63;
      u16 hv = f2bf(v);
      if (t3 == 0)      ((u16*)C0)[((long)((b_*12 + h)*1024 + n_))*64 + d] = hv;
      else if (t3 == 1) ((u16*)C1)[((long)((b_*12 + h)*1024 + n_))*64 + d] = hv;
      else              ((u16*)C2)[((long)((b_*12 + h)*64 + d))*1024 + n_] = hv;
    } else if (MODE == 1){
      ((u16*)C0)[(long)z*sC + (long)gm*N + gn] = f2bf(v);
    } else if (MODE == 2){
      int b_ = z / 12, h = z - b_*12;
      ((u16*)C0)[((long)((b_*1024 + gm)*12 + h))*64 + gn] = f2bf(v);
    } else {
      ((float*)C0)[(long)gm*N + gn] = v + bias[gn];
    }
  }
}

// Two waves per (b,n) row; each lane owns 8 contiguous m (thread t -> m = t*8..t*8+7).
// smix[12][8] = 96 live VGPRs; waves_per_eu(3,3) pins the budget at 170 -> no spill.
// S logits arrive pre-scaled (ATT_SCALE folded into w_qkv q-rows).
__global__ __launch_bounds__(128) __attribute__((amdgpu_waves_per_eu(3,3)))
void mix_kernel(
    u16* __restrict__ S, const float* __restrict__ mask,
    const float* __restrict__ w_pre, const float* __restrict__ w_post)
{
  const int bid = blockIdx.x;            // 0..4095 = b*1024 + n
  const int b = bid >> 10, n = bid & 1023;
  const int t = threadIdx.x;             // 0..127
  const int wv = t >> 6, lane = t & 63;
  const int moff = t * 8;
  const long base0 = (((long)(b*12))*1024 + n) * 1024;   // h=0 plane, row n

  float smix[12][8];

  // ---- pre-mix: smix[g] = sum_h w_pre[g,h] * S_h ----
  #pragma unroll
  for (int h=0; h<12; h++){
    uint4 raw = *reinterpret_cast<const uint4*>(S + base0 + (long)h*1024*1024 + moff);
    float sv[8];
    sv[0]=bflo(raw.x); sv[1]=bfhi(raw.x);
    sv[2]=bflo(raw.y); sv[3]=bfhi(raw.y);
    sv[4]=bflo(raw.z); sv[5]=bfhi(raw.z);
    sv[6]=bflo(raw.w); sv[7]=bfhi(raw.w);
    if (h == 0){
      #pragma unroll
      for (int g=0;g<12;g++){
        float w = w_pre[g*12];
        #pragma unroll
        for (int mi=0;mi<8;mi++) smix[g][mi] = w * sv[mi];
      }
    } else {
      #pragma unroll
      for (int g=0;g<12;g++){
        float w = w_pre[g*12 + h];
        #pragma unroll
        for (int mi=0;mi<8;mi++) smix[g][mi] += w * sv[mi];
      }
    }
  }

  // ---- mask term: + (sum_h w_pre[g,h]) * mask[b,n,m] ----
  {
    const float* mr = mask + ((long)(b*1024 + n))*1024 + moff;
    float4 a0 = *reinterpret_cast<const float4*>(mr);
    float4 a1 = *reinterpret_cast<const float4*>(mr + 4);
    float mk[8] = {a0.x,a0.y,a0.z,a0.w,a1.x,a1.y,a1.z,a1.w};
    #pragma unroll
    for (int g=0;g<12;g++){
      float rs = 0.f;
      #pragma unroll
      for (int h=0;h<12;h++) rs += w_pre[g*12 + h];   // uniform -> SALU
      #pragma unroll
      for (int mi=0;mi<8;mi++) smix[g][mi] += rs * mk[mi];
    }
  }

  // ---- softmax: 8 local + 6-step in-wave shuffle + tiny 2-wave LDS exchange ----
  __shared__ float redM[2][12];
  __shared__ float redS[2][12];
  float M[12];
  #pragma unroll
  for (int g=0;g<12;g++){
    float a = fmaxf(fmaxf(smix[g][0], smix[g][1]), fmaxf(smix[g][2], smix[g][3]));
    float c = fmaxf(fmaxf(smix[g][4], smix[g][5]), fmaxf(smix[g][6], smix[g][7]));
    M[g] = fmaxf(a, c);
  }
  #pragma unroll
  for (int off=32; off>0; off>>=1)
    #pragma unroll
    for (int g=0;g<12;g++) M[g] = fmaxf(M[g], __shfl_xor(M[g], off));
  if (lane == 0){
    #pragma unroll
    for (int g=0;g<12;g++) redM[wv][g] = M[g];
  }
  __syncthreads();
  #pragma unroll
  for (int g=0;g<12;g++) M[g] = fmaxf(redM[0][g], redM[1][g]);

  float L[12];
  #pragma unroll
  for (int g=0;g<12;g++){
    float sum = 0.f;
    #pragma unroll
    for (int mi=0;mi<8;mi++){
      float e = __expf(smix[g][mi] - M[g]);
      smix[g][mi] = e; sum += e;
    }
    L[g] = sum;
  }
  #pragma unroll
  for (int off=32; off>0; off>>=1)
    #pragma unroll
    for (int g=0;g<12;g++) L[g] += __shfl_xor(L[g], off);
  if (lane == 0){
    #pragma unroll
    for (int g=0;g<12;g++) redS[wv][g] = L[g];
  }
  __syncthreads();
  #pragma unroll
  for (int g=0;g<12;g++){
    float inv = 1.0f / (redS[0][g] + redS[1][g]);
    #pragma unroll
    for (int mi=0;mi<8;mi++) smix[g][mi] *= inv;
  }

  // ---- post-mix + packed bf16 store, streamed per output head ----
  #pragma unroll
  for (int h=0; h<12; h++){
    float o[8];
    {
      float w = w_post[h*12];
      #pragma unroll
      for (int mi=0;mi<8;mi++) o[mi] = w * smix[0][mi];
    }
    #pragma unroll
    for (int g=1;g<12;g++){
      float w = w_post[h*12 + g];
      #pragma unroll
      for (int mi=0;mi<8;mi++) o[mi] += w * smix[g][mi];
    }
    s16x8 st;
    #pragma unroll
    for (int j=0;j<8;j++) st[j] = (short)f2bf(o[j]);
    *reinterpret_cast<s16x8*>(S + base0 + (long)h*1024*1024 + moff) = st;
  }
}

extern "C" void kernel_launch(void* const* d_in, const int* in_sizes, int n_in,
                              void* d_out, int out_size, void* d_ws, size_t ws_size,
                              hipStream_t stream)
{
  const float* x      = (const float*)d_in[0];
  const float* mask   = (const float*)d_in[1];
  const float* w_qkv  = (const float*)d_in[2];
  const float* w_proj = (const float*)d_in[3];
  const float* b_proj = (const float*)d_in[4];
  const float* w_pre  = (const float*)d_in[5];
  const float* w_post = (const float*)d_in[6];
  float* out = (float*)d_out;

  u16* xb     = (u16*)d_ws;
  u16* wqkvb  = xb     + 4096l*768;
  u16* wprojb = wqkvb  + 2304l*768;
  u16* Qb     = wprojb + 768l*768;
  u16* Kb     = Qb     + 48l*1024*64;
  u16* Vtb    = Kb     + 48l*1024*64;
  u16* tmpb   = Vtb    + 48l*1024*64;
  u16* Sb     = tmpb   + 4096l*768;
  size_t need = ((size_t)(Sb - xb) + 48ul*1024*1024) * sizeof(u16);
  if (ws_size < need) return;   // insufficient scratch: fail visibly

  const int n0 = 4096*768/4, n1 = 2304*768/4, n2 = 768*768/4;
  cvt3_kernel<<<(n0+n1+n2 + 255)/256, 256, 0, stream>>>(x, xb, n0, w_qkv, wqkvb, n1,
                                                        w_proj, wprojb, n2);

  dim3 gq(4096/128, 2304/128, 1);
  gemm_bt<128,128,0><<<gq, 256, 0, stream>>>(xb, wqkvb, Qb, Kb, Vtb, nullptr,
      4096, 2304, 768, 768, 768, 0, 0, 0);

  dim3 gs(1024/128, 1024/128, 48);
  gemm_bt<128,128,1><<<gs, 256, 0, stream>>>(Qb, Kb, Sb, nullptr, nullptr, nullptr,
      1024, 1024, 64, 64, 64, 1024l*64, 1024l*64, 1024l*1024);

  mix_kernel<<<4096, 128, 0, stream>>>(Sb, mask, w_pre, w_post);

  dim3 gp(1024/64, 1, 48);
  gemm_bt<64,64,2><<<gp, 256, 0, stream>>>(Sb, Vtb, tmpb, nullptr, nullptr, nullptr,
      1024, 64, 1024, 1024, 1024, 1024l*1024, 64l*1024, 0);

  dim3 go(4096/128, 768/128, 1);
  gemm_bt<128,128,3><<<go, 256, 0, stream>>>(tmpb, wprojb, out, nullptr, nullptr, b_proj,
      4096, 768, 768, 768, 768, 0, 0, 0);
}

// Round 4
// 248.434 us; speedup vs baseline: 1.1810x; 1.0656x over previous
//
#include <hip/hip_runtime.h>
#include <hip/hip_bf16.h>

typedef __attribute__((ext_vector_type(8))) short bf16x8;
typedef __attribute__((ext_vector_type(8))) short s16x8;
typedef __attribute__((ext_vector_type(4))) float f32x4;
typedef __attribute__((ext_vector_type(2))) float f32x2;
typedef unsigned short u16;
typedef unsigned int u32;

__device__ __forceinline__ u16 f2bf(float f){
  __hip_bfloat16 h = __float2bfloat16(f);
  return *reinterpret_cast<u16*>(&h);
}
__device__ __forceinline__ float bflo(u32 w){ return __uint_as_float(w << 16); }
__device__ __forceinline__ float bfhi(u32 w){ return __uint_as_float(w & 0xffff0000u); }

// async global->LDS, 16B per lane. LDS dest is wave-uniform base + lane*16 (linear).
__device__ __forceinline__ void gload_lds16(const u16* g, u16* l){
  __builtin_amdgcn_global_load_lds(
      (__attribute__((address_space(1))) u32*)g,
      (__attribute__((address_space(3))) u32*)l, 16, 0, 0);
}

// Merged f32->bf16 convert for x / w_qkv / w_proj.
// w_qkv rows 0..767 (q-projection rows) pre-scaled by ATT_SCALE=0.125 so the
// scores GEMM directly produces scaled logits.
__global__ __launch_bounds__(256) void cvt3_kernel(
    const float* __restrict__ s0, u16* __restrict__ d0, int n0,
    const float* __restrict__ s1, u16* __restrict__ d1, int n1,
    const float* __restrict__ s2, u16* __restrict__ d2, int n2)
{
  int i = blockIdx.x*256 + threadIdx.x;
  const float* s; u16* d; int idx; float sc = 1.f;
  if (i < n0){ s = s0; d = d0; idx = i; }
  else if (i < n0 + n1){
    idx = i - n0; s = s1; d = d1;
    if (idx < 768*192) sc = 0.125f;          // f4-index < 768 rows * 192 f4/row
  } else if (i < n0 + n1 + n2){
    idx = i - n0 - n1; s = s2; d = d2;
  } else return;
  float4 v = reinterpret_cast<const float4*>(s)[idx];
  ushort4 o;
  o.x = f2bf(v.x*sc); o.y = f2bf(v.y*sc); o.z = f2bf(v.z*sc); o.w = f2bf(v.w*sc);
  reinterpret_cast<ushort4*>(d)[idx] = o;
}

// C = A(MxK) * B(NxK)^T, A/B bf16 row-major, batched over blockIdx.z.
// Staging via global_load_lds width=16 into linear [rows][BK] LDS tiles.
// MODE 0: QKV scatter -> Q[B,H,N,D](C0), K[B,H,N,D](C1), Vt[B,H,D,N](C2)
// MODE 1: bf16 store, batch stride sC (scores)
// MODE 2: PV -> tmp[B,N,H,D] bf16 (z = b*12+h)
// MODE 3: fp32 store + bias (projection)
template<int BM, int BN, int MODE>
__global__ __launch_bounds__(256) void gemm_bt(
    const u16* __restrict__ A, const u16* __restrict__ B,
    void* __restrict__ C0, void* __restrict__ C1, void* __restrict__ C2,
    const float* __restrict__ bias,
    int M, int N, int K, int lda, int ldb, long sA, long sB, long sC)
{
  constexpr int BK = 32, LDT = 32;   // linear: required by global_load_lds
  __shared__ __align__(16) u16 As[BM*LDT];
  __shared__ __align__(16) u16 Bs[BN*LDT];
  const int z = blockIdx.z;
  const u16* Ab = A + (long)z * sA;
  const u16* Bb = B + (long)z * sB;
  const int bm = blockIdx.x * BM, bn = blockIdx.y * BN;
  const int tid = threadIdx.x, lane = tid & 63, wv = tid >> 6;
  constexpr int WM = BM/2, WN = BN/2, FM = WM/16, FN = WN/16;
  const int wm = (wv >> 1) * WM, wn = (wv & 1) * WN;
  const int quad = lane >> 4, cl = lane & 15;
  f32x4 acc[FM][FN];
  #pragma unroll
  for (int i=0;i<FM;i++)
    #pragma unroll
    for (int j=0;j<FN;j++){ f32x4 zr = {0.f,0.f,0.f,0.f}; acc[i][j] = zr; }
  constexpr int AIT = (BM*BK)/(8*256);
  constexpr int BIT = (BN*BK)/(8*256);

  for (int kb = 0; kb < K; kb += BK){
    __syncthreads();
    #pragma unroll
    for (int sL=0; sL<AIT; sL++){
      int e = tid + sL*256, r = e >> 2, c8 = (e & 3) * 8;
      gload_lds16(Ab + (long)(bm + r)*lda + kb + c8, &As[e*8]);
    }
    #pragma unroll
    for (int sL=0; sL<BIT; sL++){
      int e = tid + sL*256, r = e >> 2, c8 = (e & 3) * 8;
      gload_lds16(Bb + (long)(bn + r)*ldb + kb + c8, &Bs[e*8]);
    }
    __syncthreads();   // compiler drains vmcnt before barrier
    bf16x8 af[FM], bfr[FN];
    #pragma unroll
    for (int i=0;i<FM;i++)
      af[i] = *reinterpret_cast<const bf16x8*>(&As[(wm + i*16 + cl)*LDT + quad*8]);
    #pragma unroll
    for (int j=0;j<FN;j++)
      bfr[j] = *reinterpret_cast<const bf16x8*>(&Bs[(wn + j*16 + cl)*LDT + quad*8]);
    #pragma unroll
    for (int i=0;i<FM;i++)
      #pragma unroll
      for (int j=0;j<FN;j++)
        acc[i][j] = __builtin_amdgcn_mfma_f32_16x16x32_bf16(af[i], bfr[j], acc[i][j], 0, 0, 0);
  }

  #pragma unroll
  for (int i=0;i<FM;i++)
  #pragma unroll
  for (int j=0;j<FN;j++)
  #pragma unroll
  for (int r=0;r<4;r++){
    int gm = bm + wm + i*16 + quad*4 + r;
    int gn = bn + wn + j*16 + cl;
    float v = acc[i][j][r];
    if (MODE == 0){
      int b_ = gm >> 10, n_ = gm & 1023;
      int t3 = (gn >= 1536) ? 2 : ((gn >= 768) ? 1 : 0);
      int rem = gn - t3*768;
      int h = rem >> 6, d = rem & 63;
      u16 hv = f2bf(v);
      if (t3 == 0)      ((u16*)C0)[((long)((b_*12 + h)*1024 + n_))*64 + d] = hv;
      else if (t3 == 1) ((u16*)C1)[((long)((b_*12 + h)*1024 + n_))*64 + d] = hv;
      else              ((u16*)C2)[((long)((b_*12 + h)*64 + d))*1024 + n_] = hv;
    } else if (MODE == 1){
      ((u16*)C0)[(long)z*sC + (long)gm*N + gn] = f2bf(v);
    } else if (MODE == 2){
      int b_ = z / 12, h = z - b_*12;
      ((u16*)C0)[((long)((b_*1024 + gm)*12 + h))*64 + gn] = f2bf(v);
    } else {
      ((float*)C0)[(long)gm*N + gn] = v + bias[gn];
    }
  }
}

// Four waves per (b,n) row; each lane owns 4 m (thread t -> m = t*4..t*4+3) held as
// two f32x2 so the 12x12 mixes run on v_pk_fma_f32 (dual-issue packed f32).
// smix[12][2] f32x2 = 48 f32 regs; raw preload 24; no spill, no occupancy pin.
__global__ __launch_bounds__(256) void mix_kernel(
    u16* __restrict__ S, const float* __restrict__ mask,
    const float* __restrict__ w_pre, const float* __restrict__ w_post)
{
  const int bid = blockIdx.x;            // 0..4095 = b*1024 + n
  const int b = bid >> 10, n = bid & 1023;
  const int t = threadIdx.x;             // 0..255
  const int wv = t >> 6, lane = t & 63;
  const int m0 = t * 4;
  const long base0 = (((long)(b*12))*1024 + n) * 1024;   // h=0 plane, row n

  // ---- issue all VMEM up front: 12 S-plane reads (8B) + mask (16B) ----
  uint2 raw[12];
  #pragma unroll
  for (int h=0; h<12; h++)
    raw[h] = *reinterpret_cast<const uint2*>(S + base0 + (long)h*1024*1024 + m0);
  float4 mk4 = *reinterpret_cast<const float4*>(mask + ((long)(b*1024 + n))*1024 + m0);

  // ---- pre-mix: smix[g] = (sum_h w_pre[g,h])*mask + sum_h w_pre[g,h]*S_h ----
  f32x2 smix[12][2];
  {
    f32x2 mkA = {mk4.x, mk4.y}, mkB = {mk4.z, mk4.w};
    #pragma unroll
    for (int g=0; g<12; g++){
      float rs = 0.f;
      #pragma unroll
      for (int h=0; h<12; h++) rs += w_pre[g*12 + h];   // uniform -> SALU
      smix[g][0] = rs * mkA;
      smix[g][1] = rs * mkB;
    }
  }
  #pragma unroll
  for (int h=0; h<12; h++){
    f32x2 s0 = {bflo(raw[h].x), bfhi(raw[h].x)};
    f32x2 s1 = {bflo(raw[h].y), bfhi(raw[h].y)};
    #pragma unroll
    for (int g=0; g<12; g++){
      float w = w_pre[g*12 + h];
      smix[g][0] += w * s0;
      smix[g][1] += w * s1;
    }
  }

  // ---- softmax: 4 local + 6-step shuffle + 4-wave LDS combine ----
  __shared__ float redM[12][4];
  __shared__ float redS[12][4];
  float M[12];
  #pragma unroll
  for (int g=0; g<12; g++)
    M[g] = fmaxf(fmaxf(smix[g][0][0], smix[g][0][1]),
                 fmaxf(smix[g][1][0], smix[g][1][1]));
  #pragma unroll
  for (int off=32; off>0; off>>=1)
    #pragma unroll
    for (int g=0; g<12; g++) M[g] = fmaxf(M[g], __shfl_xor(M[g], off));
  if (lane == 0){
    #pragma unroll
    for (int g=0; g<12; g++) redM[g][wv] = M[g];
  }
  __syncthreads();
  #pragma unroll
  for (int g=0; g<12; g++)
    M[g] = fmaxf(fmaxf(redM[g][0], redM[g][1]), fmaxf(redM[g][2], redM[g][3]));

  float L[12];
  #pragma unroll
  for (int g=0; g<12; g++){
    smix[g][0] -= M[g];
    smix[g][1] -= M[g];
    float e0 = __expf(smix[g][0][0]);
    float e1 = __expf(smix[g][0][1]);
    float e2 = __expf(smix[g][1][0]);
    float e3 = __expf(smix[g][1][1]);
    smix[g][0][0]=e0; smix[g][0][1]=e1; smix[g][1][0]=e2; smix[g][1][1]=e3;
    L[g] = (e0 + e1) + (e2 + e3);
  }
  #pragma unroll
  for (int off=32; off>0; off>>=1)
    #pragma unroll
    for (int g=0; g<12; g++) L[g] += __shfl_xor(L[g], off);
  if (lane == 0){
    #pragma unroll
    for (int g=0; g<12; g++) redS[g][wv] = L[g];
  }
  __syncthreads();
  #pragma unroll
  for (int g=0; g<12; g++){
    float Lt = (redS[g][0] + redS[g][1]) + (redS[g][2] + redS[g][3]);
    float inv;
    asm("v_rcp_f32 %0, %1" : "=v"(inv) : "v"(Lt));   // ~1ulp, << bf16 noise
    smix[g][0] *= inv;
    smix[g][1] *= inv;
  }

  // ---- post-mix + packed bf16 store, streamed per output head ----
  #pragma unroll
  for (int h=0; h<12; h++){
    f32x2 o0, o1;
    {
      float w = w_post[h*12];
      o0 = w * smix[0][0];
      o1 = w * smix[0][1];
    }
    #pragma unroll
    for (int g=1; g<12; g++){
      float w = w_post[h*12 + g];
      o0 += w * smix[g][0];
      o1 += w * smix[g][1];
    }
    ushort4 st;
    st.x = f2bf(o0[0]); st.y = f2bf(o0[1]);
    st.z = f2bf(o1[0]); st.w = f2bf(o1[1]);
    *reinterpret_cast<ushort4*>(S + base0 + (long)h*1024*1024 + m0) = st;
  }
}

extern "C" void kernel_launch(void* const* d_in, const int* in_sizes, int n_in,
                              void* d_out, int out_size, void* d_ws, size_t ws_size,
                              hipStream_t stream)
{
  const float* x      = (const float*)d_in[0];
  const float* mask   = (const float*)d_in[1];
  const float* w_qkv  = (const float*)d_in[2];
  const float* w_proj = (const float*)d_in[3];
  const float* b_proj = (const float*)d_in[4];
  const float* w_pre  = (const float*)d_in[5];
  const float* w_post = (const float*)d_in[6];
  float* out = (float*)d_out;

  u16* xb     = (u16*)d_ws;
  u16* wqkvb  = xb     + 4096l*768;
  u16* wprojb = wqkvb  + 2304l*768;
  u16* Qb     = wprojb + 768l*768;
  u16* Kb     = Qb     + 48l*1024*64;
  u16* Vtb    = Kb     + 48l*1024*64;
  u16* tmpb   = Vtb    + 48l*1024*64;
  u16* Sb     = tmpb   + 4096l*768;
  size_t need = ((size_t)(Sb - xb) + 48ul*1024*1024) * sizeof(u16);
  if (ws_size < need) return;   // insufficient scratch: fail visibly

  const int n0 = 4096*768/4, n1 = 2304*768/4, n2 = 768*768/4;
  cvt3_kernel<<<(n0+n1+n2 + 255)/256, 256, 0, stream>>>(x, xb, n0, w_qkv, wqkvb, n1,
                                                        w_proj, wprojb, n2);

  dim3 gq(4096/128, 2304/128, 1);
  gemm_bt<128,128,0><<<gq, 256, 0, stream>>>(xb, wqkvb, Qb, Kb, Vtb, nullptr,
      4096, 2304, 768, 768, 768, 0, 0, 0);

  dim3 gs(1024/128, 1024/128, 48);
  gemm_bt<128,128,1><<<gs, 256, 0, stream>>>(Qb, Kb, Sb, nullptr, nullptr, nullptr,
      1024, 1024, 64, 64, 64, 1024l*64, 1024l*64, 1024l*1024);

  mix_kernel<<<4096, 256, 0, stream>>>(Sb, mask, w_pre, w_post);

  dim3 gp(1024/64, 1, 48);
  gemm_bt<64,64,2><<<gp, 256, 0, stream>>>(Sb, Vtb, tmpb, nullptr, nullptr, nullptr,
      1024, 64, 1024, 1024, 1024, 1024l*1024, 64l*1024, 0);

  dim3 go(4096/128, 768/128, 1);
  gemm_bt<128,128,3><<<go, 256, 0, stream>>>(tmpb, wprojb, out, nullptr, nullptr, b_proj,
      4096, 768, 768, 768, 768, 0, 0, 0);
}